// Round 4
// baseline (253.128 us; speedup 1.0000x reference)
//
#include <hip/hip_runtime.h>

#define HID 64
#define FEAT 10
#define MAXSEG 8192        // fixed per-bucket segment (mean fill 4081, 64 sigma margin)

typedef unsigned short u16;

// ---------- helpers ----------
__device__ __forceinline__ u16 f2bf(float f) {            // fp32 -> bf16 RNE
    unsigned u = __float_as_uint(f);
    unsigned r = (u + 0x7fffu + ((u >> 16) & 1u)) >> 16;
    return (u16)r;
}
__device__ __forceinline__ void bf8_add(float* acc, uint4 u) {
    acc[0] += __uint_as_float(u.x << 16);
    acc[1] += __uint_as_float(u.x & 0xffff0000u);
    acc[2] += __uint_as_float(u.y << 16);
    acc[3] += __uint_as_float(u.y & 0xffff0000u);
    acc[4] += __uint_as_float(u.z << 16);
    acc[5] += __uint_as_float(u.z & 0xffff0000u);
    acc[6] += __uint_as_float(u.w << 16);
    acc[7] += __uint_as_float(u.w & 0xffff0000u);
}

// ================= CSR build (2 kernels) =================

// One pass over edges: LDS histogram -> global range reservation -> emit from registers.
// Bucket b owns tmp[b*MAXSEG .. b*MAXSEG+cnt). Also writes hwb/xp sentinel rows (block 0).
__global__ void bin_kernel(const int* __restrict__ src, const int* __restrict__ dst,
                           int* __restrict__ gcnt, unsigned* __restrict__ tmp,
                           u16* __restrict__ hwb, u16* __restrict__ xp,
                           int E, int N) {
    __shared__ int h[256];           // histogram, then current-slot cursors
    int t = threadIdx.x, c = blockIdx.x;
    if (t < 256) h[t] = 0;
    __syncthreads();
    int b0 = c * 4096;
    unsigned pk[4]; int bk[4];
    #pragma unroll
    for (int j = 0; j < 4; j++) {
        int e = b0 + t + j * 1024;
        if (e < E) {
            int s = src[e], d = dst[e];
            pk[j] = ((unsigned)(d & 255) << 16) | (unsigned)s;
            bk[j] = d >> 8;
            atomicAdd(&h[bk[j]], 1);
        } else bk[j] = -1;
    }
    __syncthreads();
    if (t < 256) {
        int v = h[t];
        int resv = v ? atomicAdd(&gcnt[t], v) : 0;
        h[t] = t * MAXSEG + resv;    // cursor = fixed bucket base + reserved offset
    }
    __syncthreads();
    #pragma unroll
    for (int j = 0; j < 4; j++) {
        if (bk[j] >= 0) {
            int slot = atomicAdd(&h[bk[j]], 1);
            tmp[slot] = pk[j];
        }
    }
    if (c == 0) {                    // sentinel rows (node N): zero
        if (t < 64)      hwb[(size_t)N * 64 + t] = 0;
        else if (t < 80) xp[(size_t)N * 16 + (t - 64)] = 0;
    }
}

// per-bucket node-sort into padded u16 CSR + row metadata + dinv + pad_x
// + degree-sorted node permutation (counting sort by padL>>3) for divergence-free gathers
__global__ void csr_build(const unsigned* __restrict__ tmp, const int* __restrict__ gcnt,
                          u16* __restrict__ csr2,
                          int* __restrict__ row_start, int* __restrict__ row_cntp,
                          float* __restrict__ dinv, int* __restrict__ perm,
                          const float* __restrict__ x, u16* __restrict__ xp, int N) {
    __shared__ __align__(16) u16 staged[MAXSEG];
    __shared__ int cntL[256], padL[256], scanL[256], curL[256];
    __shared__ float sdinv[256];
    __shared__ int h32[32], o32[32];
    int b = blockIdx.x, t = threadIdx.x;          // 1024 threads
    if (t < 256) cntL[t] = 0;
    if (t < 32) h32[t] = 0;
    for (int i = t; i < MAXSEG; i += 1024) staged[i] = (u16)N;   // sentinel prefill
    __syncthreads();
    int segBase = b * MAXSEG, segLen = gcnt[b];
    for (int i = t; i < segLen; i += 1024)
        atomicAdd(&cntL[tmp[segBase + i] >> 16], 1);
    __syncthreads();
    if (t < 256) { padL[t] = (cntL[t] + 7) & ~7; scanL[t] = padL[t]; }
    __syncthreads();
    for (int off = 1; off < 256; off <<= 1) {
        int a = (t < 256) ? scanL[t] : 0;
        int s = (t >= off && t < 256) ? scanL[t - off] : 0;
        __syncthreads();
        if (t < 256) scanL[t] = a + s;
        __syncthreads();
    }
    int key = 0;
    if (t < 256) {
        int excl = scanL[t] - padL[t];
        curL[t] = excl;
        float dv = rsqrtf((float)cntL[t] + 1.0f);
        sdinv[t] = dv;
        int node = b * 256 + t;
        if (node < N) {
            row_start[node] = b * MAXSEG + excl;
            row_cntp[node]  = padL[t];
            dinv[node]      = dv;
        }
        key = min(padL[t] >> 3, 31);
        atomicAdd(&h32[key], 1);
    }
    __syncthreads();
    if (t == 0) {
        int run = 0;
        for (int k2 = 0; k2 < 32; k2++) { o32[k2] = run; run += h32[k2]; }
    }
    __syncthreads();
    if (t < 256) {
        int pos = atomicAdd(&o32[key], 1);
        perm[b * 256 + pos] = b * 256 + t;      // bucket-local degree-sorted order
    }
    __syncthreads();
    for (int i = t; i < segLen; i += 1024) {
        unsigned e = tmp[segBase + i];
        int idx = atomicAdd(&curL[e >> 16], 1);
        staged[idx] = (u16)(e & 0xffffu);
    }
    // pad_x for this bucket's 256 nodes (independent of staged[])
    for (int i = t; i < 256 * 16; i += 1024) {
        int nlc = i >> 4, cch = i & 15;
        int node = b * 256 + nlc;
        if (node < N)
            xp[(size_t)node * 16 + cch] =
                (cch < FEAT) ? f2bf(sdinv[nlc] * x[(size_t)node * FEAT + cch]) : (u16)0;
    }
    __syncthreads();
    ((uint4*)(csr2 + (size_t)b * MAXSEG))[t] = ((const uint4*)staged)[t];
}

// ================= layer 1: gather_x + mm1 fused through LDS =================

__global__ void gxmm1(const int* __restrict__ perm,
                      const int* __restrict__ row_start, const int* __restrict__ row_cntp,
                      const u16* __restrict__ csr2, const u16* __restrict__ xp,
                      const float* __restrict__ dinv,
                      const float* __restrict__ W1, const float* __restrict__ b1,
                      float* __restrict__ hf, int N) {
    __shared__ float sW[FEAT * 64];
    __shared__ float sH[64 * 16];
    int t = threadIdx.x;
    int slot0 = blockIdx.x * 64;
    for (int i = t; i < FEAT * 64; i += 256) sW[i] = W1[i];
    if (t < 128) {
        int nl = t >> 1;
        int node = perm[slot0 + nl];
        int c0 = (t & 1) * 8;
        float acc[8] = {0.f,0.f,0.f,0.f,0.f,0.f,0.f,0.f};
        if (node < N) {
            uint4 sv = *(const uint4*)(xp + (size_t)node * 16 + c0);
            bf8_add(acc, sv);
            int i0 = row_start[node], cnt = row_cntp[node];
            if (cnt) {
                int iE = i0 + cnt;
                uint4 ev = *(const uint4*)(csr2 + i0);
                for (int i = i0; i < iE; i += 8) {
                    uint4 evn = *(const uint4*)(csr2 + i + 8);   // pipeline (slack-safe)
                    int s0 = ev.x & 0xffff, s1 = ev.x >> 16;
                    int s2 = ev.y & 0xffff, s3 = ev.y >> 16;
                    int s4 = ev.z & 0xffff, s5 = ev.z >> 16;
                    int s6 = ev.w & 0xffff, s7 = ev.w >> 16;
                    uint4 u0 = *(const uint4*)(xp + (size_t)s0 * 16 + c0);
                    uint4 u1 = *(const uint4*)(xp + (size_t)s1 * 16 + c0);
                    uint4 u2 = *(const uint4*)(xp + (size_t)s2 * 16 + c0);
                    uint4 u3 = *(const uint4*)(xp + (size_t)s3 * 16 + c0);
                    uint4 u4 = *(const uint4*)(xp + (size_t)s4 * 16 + c0);
                    uint4 u5 = *(const uint4*)(xp + (size_t)s5 * 16 + c0);
                    uint4 u6 = *(const uint4*)(xp + (size_t)s6 * 16 + c0);
                    uint4 u7 = *(const uint4*)(xp + (size_t)s7 * 16 + c0);
                    bf8_add(acc, u0); bf8_add(acc, u1); bf8_add(acc, u2); bf8_add(acc, u3);
                    bf8_add(acc, u4); bf8_add(acc, u5); bf8_add(acc, u6); bf8_add(acc, u7);
                    ev = evn;
                }
            }
            float di = dinv[node];
            #pragma unroll
            for (int j = 0; j < 8; j++) acc[j] *= di;
        }
        #pragma unroll
        for (int j = 0; j < 8; j++) sH[nl * 16 + c0 + j] = acc[j];
    }
    __syncthreads();
    int c0 = (t & 15) * 4;
    int rbase = (t >> 4) * 4;
    float4 a0 = {0,0,0,0}, a1 = {0,0,0,0}, a2 = {0,0,0,0}, a3 = {0,0,0,0};
    for (int k = 0; k < FEAT; k++) {
        float4 w = *(const float4*)(sW + k * 64 + c0);
        float h0 = sH[(rbase + 0) * 16 + k];
        float h1v = sH[(rbase + 1) * 16 + k];
        float h2 = sH[(rbase + 2) * 16 + k];
        float h3 = sH[(rbase + 3) * 16 + k];
        a0.x += h0 * w.x; a0.y += h0 * w.y; a0.z += h0 * w.z; a0.w += h0 * w.w;
        a1.x += h1v * w.x; a1.y += h1v * w.y; a1.z += h1v * w.z; a1.w += h1v * w.w;
        a2.x += h2 * w.x; a2.y += h2 * w.y; a2.z += h2 * w.z; a2.w += h2 * w.w;
        a3.x += h3 * w.x; a3.y += h3 * w.y; a3.z += h3 * w.z; a3.w += h3 * w.w;
    }
    float4 bb = *(const float4*)(b1 + c0);
    float4 accs[4] = {a0, a1, a2, a3};
    for (int rr = 0; rr < 4; rr++) {
        int node = perm[slot0 + rbase + rr];
        if (node < N) {
            float4 v = accs[rr];
            v.x = fmaxf(v.x + bb.x, 0.f); v.y = fmaxf(v.y + bb.y, 0.f);
            v.z = fmaxf(v.z + bb.z, 0.f); v.w = fmaxf(v.w + bb.w, 0.f);
            *(float4*)(hf + (size_t)node * 64 + c0) = v;
        }
    }
}

// ================= layers 2/3 =================

__global__ void gcn_matmul64(const float* __restrict__ h_in, const float* __restrict__ W,
                             const float* __restrict__ dinv, u16* __restrict__ hwb, int N) {
    __shared__ float sW[64 * 64];
    __shared__ float sH[64 * 65];
    int t = threadIdx.x;
    int node0 = blockIdx.x * 64;
    for (int i = t * 4; i < 4096; i += 1024)
        *(float4*)(sW + i) = *(const float4*)(W + i);
    for (int i = t; i < 4096; i += 256) {
        int r = i >> 6, k = i & 63;
        int node = node0 + r;
        sH[r * 65 + k] = (node < N) ? h_in[(size_t)node * 64 + k] : 0.0f;
    }
    __syncthreads();
    int c0 = (t & 15) * 4;
    int rbase = (t >> 4) * 4;
    float4 a0 = {0,0,0,0}, a1 = {0,0,0,0}, a2 = {0,0,0,0}, a3 = {0,0,0,0};
    for (int k = 0; k < 64; k++) {
        float4 w = *(const float4*)(sW + k * 64 + c0);
        float h0 = sH[(rbase + 0) * 65 + k];
        float h1v = sH[(rbase + 1) * 65 + k];
        float h2 = sH[(rbase + 2) * 65 + k];
        float h3 = sH[(rbase + 3) * 65 + k];
        a0.x += h0 * w.x; a0.y += h0 * w.y; a0.z += h0 * w.z; a0.w += h0 * w.w;
        a1.x += h1v * w.x; a1.y += h1v * w.y; a1.z += h1v * w.z; a1.w += h1v * w.w;
        a2.x += h2 * w.x; a2.y += h2 * w.y; a2.z += h2 * w.z; a2.w += h2 * w.w;
        a3.x += h3 * w.x; a3.y += h3 * w.y; a3.z += h3 * w.z; a3.w += h3 * w.w;
    }
    float4 accs[4] = {a0, a1, a2, a3};
    for (int rr = 0; rr < 4; rr++) {
        int node = node0 + rbase + rr;
        if (node >= N) break;
        float di = dinv[node];
        float4 v = accs[rr];
        ushort4 o;
        o.x = f2bf(v.x * di); o.y = f2bf(v.y * di);
        o.z = f2bf(v.z * di); o.w = f2bf(v.w * di);
        *(ushort4*)(hwb + (size_t)node * 64 + c0) = o;
    }
}

// 8 lanes per node, each lane owns 8 channels (16B). Nodes walked in degree-sorted
// perm order -> waves carry near-equal trip counts (no max-of-8 divergence).
__global__ void gather_bf(const int* __restrict__ perm,
                          const int* __restrict__ row_start, const int* __restrict__ row_cntp,
                          const u16* __restrict__ csr2, const u16* __restrict__ hwb,
                          const float* __restrict__ dinv, const float* __restrict__ b,
                          float* __restrict__ out, float* __restrict__ gsum,
                          int N, int do_gsum) {
    int t = threadIdx.x;
    int nl = t >> 3;                       // 0..31 node slot in block
    int node = perm[blockIdx.x * 32 + nl];
    int c0 = (t & 7) * 8;                  // first of this lane's 8 channels
    float acc[8] = {0.f,0.f,0.f,0.f,0.f,0.f,0.f,0.f};
    if (node < N) {
        uint4 sv = *(const uint4*)(hwb + (size_t)node * 64 + c0);
        bf8_add(acc, sv);
        int i0 = row_start[node], cnt = row_cntp[node];
        if (cnt) {
            int iE = i0 + cnt;
            uint4 ev = *(const uint4*)(csr2 + i0);
            for (int i = i0; i < iE; i += 8) {
                uint4 evn = *(const uint4*)(csr2 + i + 8);   // pipeline (slack-safe)
                int s0 = ev.x & 0xffff, s1 = ev.x >> 16;
                int s2 = ev.y & 0xffff, s3 = ev.y >> 16;
                int s4 = ev.z & 0xffff, s5 = ev.z >> 16;
                int s6 = ev.w & 0xffff, s7 = ev.w >> 16;
                uint4 u0 = *(const uint4*)(hwb + (size_t)s0 * 64 + c0);
                uint4 u1 = *(const uint4*)(hwb + (size_t)s1 * 64 + c0);
                uint4 u2 = *(const uint4*)(hwb + (size_t)s2 * 64 + c0);
                uint4 u3 = *(const uint4*)(hwb + (size_t)s3 * 64 + c0);
                uint4 u4 = *(const uint4*)(hwb + (size_t)s4 * 64 + c0);
                uint4 u5 = *(const uint4*)(hwb + (size_t)s5 * 64 + c0);
                uint4 u6 = *(const uint4*)(hwb + (size_t)s6 * 64 + c0);
                uint4 u7 = *(const uint4*)(hwb + (size_t)s7 * 64 + c0);
                bf8_add(acc, u0); bf8_add(acc, u1); bf8_add(acc, u2); bf8_add(acc, u3);
                bf8_add(acc, u4); bf8_add(acc, u5); bf8_add(acc, u6); bf8_add(acc, u7);
                ev = evn;
            }
        }
        float di = dinv[node];
        const float4 bb0 = *(const float4*)(b + c0);
        const float4 bb1 = *(const float4*)(b + c0 + 4);
        float4 o0, o1;
        o0.x = fmaxf(acc[0]*di + bb0.x, 0.f); o0.y = fmaxf(acc[1]*di + bb0.y, 0.f);
        o0.z = fmaxf(acc[2]*di + bb0.z, 0.f); o0.w = fmaxf(acc[3]*di + bb0.w, 0.f);
        o1.x = fmaxf(acc[4]*di + bb1.x, 0.f); o1.y = fmaxf(acc[5]*di + bb1.y, 0.f);
        o1.z = fmaxf(acc[6]*di + bb1.z, 0.f); o1.w = fmaxf(acc[7]*di + bb1.w, 0.f);
        *(float4*)(out + (size_t)node * 64 + c0)     = o0;
        *(float4*)(out + (size_t)node * 64 + c0 + 4) = o1;
        acc[0]=o0.x; acc[1]=o0.y; acc[2]=o0.z; acc[3]=o0.w;
        acc[4]=o1.x; acc[5]=o1.y; acc[6]=o1.z; acc[7]=o1.w;
    }
    if (do_gsum) {
        __shared__ float red[32 * 64];
        #pragma unroll
        for (int j = 0; j < 8; j++) red[nl * 64 + c0 + j] = acc[j];
        __syncthreads();
        if (t < 64) {
            float s = 0.f;
            #pragma unroll 8
            for (int k = 0; k < 32; k++) s += red[k * 64 + t];
            atomicAdd(&gsum[t], s);
        }
    }
}

// ================= head =================

__global__ void final_kernel(const float* __restrict__ h3, const int* __restrict__ sheet_idx,
                             const float* __restrict__ sheet_feat, const float* __restrict__ g_sum,
                             const float* __restrict__ gW1, const float* __restrict__ gb1,
                             const float* __restrict__ gW2, const float* __restrict__ gb2,
                             const float* __restrict__ fW,  const float* __restrict__ fb,
                             const float* __restrict__ qW1, const float* __restrict__ qb1,
                             const float* __restrict__ qW2, const float* __restrict__ qb2,
                             float* __restrict__ out, int N, int L) {
    int s = blockIdx.x, t = threadIdx.x;
    __shared__ float red[256];
    __shared__ float semb[64];
    __shared__ float geoh[64];
    __shared__ float geo[64];
    __shared__ float hq[128];
    int c = t & 63, jg = t >> 6;
    float acc = 0.0f;
    for (int j = jg; j < L; j += 4) {
        int node = sheet_idx[s * L + j];
        acc += h3[(size_t)node * 64 + c];
    }
    red[t] = acc;
    __syncthreads();
    if (t < 64) {
        semb[t] = (red[t] + red[t + 64] + red[t + 128] + red[t + 192]) / (float)L;
        hq[64 + t] = g_sum[t] / (float)N;
        float a = gb1[t];
        #pragma unroll
        for (int k = 0; k < FEAT; k++) a += sheet_feat[s * FEAT + k] * gW1[k * 64 + t];
        geoh[t] = fmaxf(a, 0.0f);
    }
    __syncthreads();
    if (t < 64) {
        float a = gb2[t];
        for (int k = 0; k < 64; k++) a += geoh[k] * gW2[k * 64 + t];
        geo[t] = a;
    }
    __syncthreads();
    if (t < 64) {
        float a = fb[t];
        for (int k = 0; k < 64; k++) a += semb[k] * fW[k * 64 + t];
        for (int k = 0; k < 64; k++) a += geo[k]  * fW[(64 + k) * 64 + t];
        hq[t] = fmaxf(a, 0.0f);
    }
    __syncthreads();
    float q = 0.0f;
    if (t < 64) {
        float a = qb1[t];
        for (int k = 0; k < 128; k++) a += hq[k] * qW1[k * 64 + t];
        a = fmaxf(a, 0.0f);
        q = a * qW2[t];
        for (int off = 32; off > 0; off >>= 1) q += __shfl_down(q, off, 64);
        if (t == 0) out[s] = q + qb2[0];
    }
}

extern "C" void kernel_launch(void* const* d_in, const int* in_sizes, int n_in,
                              void* d_out, int out_size, void* d_ws, size_t ws_size,
                              hipStream_t stream) {
    const float* x          = (const float*)d_in[0];
    const int*   edge       = (const int*)d_in[1];
    const int*   sheet_idx  = (const int*)d_in[3];
    const float* sheet_feat = (const float*)d_in[4];
    const float* W1 = (const float*)d_in[5];  const float* b1 = (const float*)d_in[6];
    const float* W2 = (const float*)d_in[7];  const float* b2 = (const float*)d_in[8];
    const float* W3 = (const float*)d_in[9];  const float* b3 = (const float*)d_in[10];
    const float* gW1 = (const float*)d_in[11]; const float* gb1 = (const float*)d_in[12];
    const float* gW2 = (const float*)d_in[13]; const float* gb2 = (const float*)d_in[14];
    const float* fW  = (const float*)d_in[15]; const float* fb  = (const float*)d_in[16];
    const float* qW1 = (const float*)d_in[17]; const float* qb1 = (const float*)d_in[18];
    const float* qW2 = (const float*)d_in[19]; const float* qb2 = (const float*)d_in[20];
    float* out = (float*)d_out;

    int N = in_sizes[2];            // 50000
    int E = in_sizes[1] / 2;        // 800000
    int S = in_sizes[4] / FEAT;     // 256
    int L = in_sizes[3] / S;        // 128

    int nbuckets = (N + 255) / 256;     // 196 (u16 src requires N < 65535)
    int nchunks  = (E + 4095) / 4096;   // 196
    int nslots   = nbuckets * 256;      // 50176 perm slots

    char* p = (char*)d_ws;
    unsigned* tmp  = (unsigned*)p;             p += (size_t)nbuckets * MAXSEG * 4;
    u16* csr2      = (u16*)p;                  p += ((size_t)nbuckets * MAXSEG + 32) * 2; // +slack for ev prefetch
    float* hf      = (float*)p;                p += (size_t)N * 64 * 4;
    u16* hwb       = (u16*)p;                  p += (size_t)(N + 1) * 64 * 2;   // [node][64] bf16
    u16* xp        = (u16*)p;                  p += (size_t)(N + 1) * 16 * 2;
    int* row_start = (int*)p;                  p += (size_t)N * 4;
    int* row_cntp  = (int*)p;                  p += (size_t)N * 4;
    float* dinv    = (float*)p;                p += (size_t)N * 4;
    int* perm      = (int*)p;                  p += (size_t)nslots * 4;
    int* gcnt      = (int*)p;                  p += 256 * 4;
    float* gsum    = (float*)p;                p += 64 * 4;

    hipMemsetAsync(gcnt, 0, 256 * 4 + 64 * 4, stream);   // gcnt + gsum (adjacent)

    const int* src = edge;
    const int* dst = edge + E;

    int gMM = (N + 63) / 64;            // 782  (mm64: raw node order)
    int gGX = nslots / 64;              // 784  (gxmm1: perm slots)
    int gGB = nslots / 32;              // 1568 (gather: perm slots)

    bin_kernel<<<nchunks, 1024, 0, stream>>>(src, dst, gcnt, tmp, hwb, xp, E, N);
    csr_build<<<nbuckets, 1024, 0, stream>>>(tmp, gcnt, csr2, row_start, row_cntp, dinv, perm, x, xp, N);

    gxmm1<<<gGX, 256, 0, stream>>>(perm, row_start, row_cntp, csr2, xp, dinv, W1, b1, hf, N);

    gcn_matmul64<<<gMM, 256, 0, stream>>>(hf, W2, dinv, hwb, N);
    gather_bf<<<gGB, 256, 0, stream>>>(perm, row_start, row_cntp, csr2, hwb, dinv, b2, hf, gsum, N, 0);

    gcn_matmul64<<<gMM, 256, 0, stream>>>(hf, W3, dinv, hwb, N);
    gather_bf<<<gGB, 256, 0, stream>>>(perm, row_start, row_cntp, csr2, hwb, dinv, b3, hf, gsum, N, 1);

    final_kernel<<<S, 256, 0, stream>>>(hf, sheet_idx, sheet_feat, gsum,
                                        gW1, gb1, gW2, gb2, fW, fb,
                                        qW1, qb1, qW2, qb2, out, N, L);
}

// Round 5
// 242.713 us; speedup vs baseline: 1.0429x; 1.0429x over previous
//
#include <hip/hip_runtime.h>

#define HID 64
#define FEAT 10
#define MAXSEG 8192        // fixed per-bucket segment (mean fill 4081, 64 sigma margin)

typedef unsigned short u16;

// ---------- helpers ----------
__device__ __forceinline__ u16 f2bf(float f) {            // fp32 -> bf16 RNE
    unsigned u = __float_as_uint(f);
    unsigned r = (u + 0x7fffu + ((u >> 16) & 1u)) >> 16;
    return (u16)r;
}
__device__ __forceinline__ void bf8_add(float* acc, uint4 u) {
    acc[0] += __uint_as_float(u.x << 16);
    acc[1] += __uint_as_float(u.x & 0xffff0000u);
    acc[2] += __uint_as_float(u.y << 16);
    acc[3] += __uint_as_float(u.y & 0xffff0000u);
    acc[4] += __uint_as_float(u.z << 16);
    acc[5] += __uint_as_float(u.z & 0xffff0000u);
    acc[6] += __uint_as_float(u.w << 16);
    acc[7] += __uint_as_float(u.w & 0xffff0000u);
}

// ================= CSR build (2 kernels) =================

// One pass over edges: LDS histogram -> global range reservation -> emit from registers.
// Bucket b owns tmp[b*MAXSEG .. b*MAXSEG+cnt). Also zeroes sentinel rows (block 0).
__global__ __launch_bounds__(1024) void bin_kernel(
        const int* __restrict__ src, const int* __restrict__ dst,
        int* __restrict__ gcnt, unsigned* __restrict__ tmp,
        u16* __restrict__ hwba, u16* __restrict__ hwbb, u16* __restrict__ xp,
        int E, int N) {
    __shared__ int h[256];           // histogram, then current-slot cursors
    int t = threadIdx.x, c = blockIdx.x;
    if (t < 256) h[t] = 0;
    __syncthreads();
    int b0 = c * 4096;
    unsigned pk[4]; int bk[4];
    #pragma unroll
    for (int j = 0; j < 4; j++) {
        int e = b0 + t + j * 1024;
        if (e < E) {
            int s = src[e], d = dst[e];
            pk[j] = ((unsigned)(d & 255) << 16) | (unsigned)s;
            bk[j] = d >> 8;
            atomicAdd(&h[bk[j]], 1);
        } else bk[j] = -1;
    }
    __syncthreads();
    if (t < 256) {
        int v = h[t];
        int resv = v ? atomicAdd(&gcnt[t], v) : 0;
        h[t] = t * MAXSEG + resv;    // cursor = fixed bucket base + reserved offset
    }
    __syncthreads();
    #pragma unroll
    for (int j = 0; j < 4; j++) {
        if (bk[j] >= 0) {
            int slot = atomicAdd(&h[bk[j]], 1);
            tmp[slot] = pk[j];
        }
    }
    if (c == 0) {                    // sentinel rows (node N): zero
        if (t < 64)       hwba[(size_t)N * 64 + t] = 0;
        else if (t < 128) hwbb[(size_t)N * 64 + (t - 64)] = 0;
        else if (t < 144) xp[(size_t)N * 16 + (t - 128)] = 0;
    }
}

// per-bucket node-sort into padded u16 CSR + row metadata + dinv + pad_x
__global__ __launch_bounds__(1024) void csr_build(
        const unsigned* __restrict__ tmp, const int* __restrict__ gcnt,
        u16* __restrict__ csr2,
        int* __restrict__ row_start, int* __restrict__ row_cntp,
        float* __restrict__ dinv,
        const float* __restrict__ x, u16* __restrict__ xp, int N) {
    __shared__ __align__(16) u16 staged[MAXSEG];
    __shared__ int cntL[256], padL[256], scanL[256], curL[256];
    __shared__ float sdinv[256];
    int b = blockIdx.x, t = threadIdx.x;          // 1024 threads
    if (t < 256) cntL[t] = 0;
    for (int i = t; i < MAXSEG; i += 1024) staged[i] = (u16)N;   // sentinel prefill
    __syncthreads();
    int segBase = b * MAXSEG, segLen = gcnt[b];
    for (int i = t; i < segLen; i += 1024)
        atomicAdd(&cntL[tmp[segBase + i] >> 16], 1);
    __syncthreads();
    if (t < 256) { padL[t] = (cntL[t] + 7) & ~7; scanL[t] = padL[t]; }
    __syncthreads();
    for (int off = 1; off < 256; off <<= 1) {
        int a = (t < 256) ? scanL[t] : 0;
        int s = (t >= off && t < 256) ? scanL[t - off] : 0;
        __syncthreads();
        if (t < 256) scanL[t] = a + s;
        __syncthreads();
    }
    if (t < 256) {
        int excl = scanL[t] - padL[t];
        curL[t] = excl;
        float dv = rsqrtf((float)cntL[t] + 1.0f);
        sdinv[t] = dv;
        int node = b * 256 + t;
        if (node < N) {
            row_start[node] = b * MAXSEG + excl;
            row_cntp[node]  = padL[t];
            dinv[node]      = dv;
        }
    }
    __syncthreads();
    for (int i = t; i < segLen; i += 1024) {
        unsigned e = tmp[segBase + i];
        int idx = atomicAdd(&curL[e >> 16], 1);
        staged[idx] = (u16)(e & 0xffffu);
    }
    // pad_x for this bucket's 256 nodes (independent of staged[])
    for (int i = t; i < 256 * 16; i += 1024) {
        int nlc = i >> 4, cch = i & 15;
        int node = b * 256 + nlc;
        if (node < N)
            xp[(size_t)node * 16 + cch] =
                (cch < FEAT) ? f2bf(sdinv[nlc] * x[(size_t)node * FEAT + cch]) : (u16)0;
    }
    __syncthreads();
    ((uint4*)(csr2 + (size_t)b * MAXSEG))[t] = ((const uint4*)staged)[t];
}

// ================= fused layer1 (gather_x+mm1) + layer2-matmul (W2) =================
// 256 threads, 64 nodes per block. h1 never leaves LDS.

__global__ __launch_bounds__(256) void l1l2(
        const int* __restrict__ row_start, const int* __restrict__ row_cntp,
        const u16* __restrict__ csr2, const u16* __restrict__ xp,
        const float* __restrict__ dinv,
        const float* __restrict__ W1, const float* __restrict__ b1,
        const float* __restrict__ W2,
        u16* __restrict__ hwba, int N) {
    __shared__ float sW[64 * 64];        // W1 (first 640) then W2
    __shared__ float sH16[64 * 16];      // scaled aggregate of x
    __shared__ float sH64[64 * 65];      // h1
    int t = threadIdx.x;
    int node0 = blockIdx.x * 64;
    for (int i = t; i < FEAT * 64; i += 256) sW[i] = W1[i];
    if (t < 128) {
        int nl = t >> 1;
        int node = node0 + nl;
        int c0 = (t & 1) * 8;
        float acc[8] = {0.f,0.f,0.f,0.f,0.f,0.f,0.f,0.f};
        if (node < N) {
            uint4 sv = *(const uint4*)(xp + (size_t)node * 16 + c0);
            bf8_add(acc, sv);
            int i0 = row_start[node], iE = i0 + row_cntp[node];
            for (int i = i0; i < iE; i += 8) {
                uint4 ev = *(const uint4*)(csr2 + i);
                int s0 = ev.x & 0xffff, s1 = ev.x >> 16;
                int s2 = ev.y & 0xffff, s3 = ev.y >> 16;
                int s4 = ev.z & 0xffff, s5 = ev.z >> 16;
                int s6 = ev.w & 0xffff, s7 = ev.w >> 16;
                uint4 u0 = *(const uint4*)(xp + (size_t)s0 * 16 + c0);
                uint4 u1 = *(const uint4*)(xp + (size_t)s1 * 16 + c0);
                uint4 u2 = *(const uint4*)(xp + (size_t)s2 * 16 + c0);
                uint4 u3 = *(const uint4*)(xp + (size_t)s3 * 16 + c0);
                uint4 u4 = *(const uint4*)(xp + (size_t)s4 * 16 + c0);
                uint4 u5 = *(const uint4*)(xp + (size_t)s5 * 16 + c0);
                uint4 u6 = *(const uint4*)(xp + (size_t)s6 * 16 + c0);
                uint4 u7 = *(const uint4*)(xp + (size_t)s7 * 16 + c0);
                bf8_add(acc, u0); bf8_add(acc, u1); bf8_add(acc, u2); bf8_add(acc, u3);
                bf8_add(acc, u4); bf8_add(acc, u5); bf8_add(acc, u6); bf8_add(acc, u7);
            }
            float di = dinv[node];
            #pragma unroll
            for (int j = 0; j < 8; j++) acc[j] *= di;
        }
        #pragma unroll
        for (int j = 0; j < 8; j++) sH16[nl * 16 + c0 + j] = acc[j];
    }
    __syncthreads();
    // mm1: h1 = relu(agg @ W1 + b1) -> sH64
    int c0 = (t & 15) * 4;
    int rbase = (t >> 4) * 4;
    {
        float4 a0 = {0,0,0,0}, a1 = {0,0,0,0}, a2 = {0,0,0,0}, a3 = {0,0,0,0};
        for (int k = 0; k < FEAT; k++) {
            float4 w = *(const float4*)(sW + k * 64 + c0);
            float h0 = sH16[(rbase + 0) * 16 + k];
            float h1v = sH16[(rbase + 1) * 16 + k];
            float h2 = sH16[(rbase + 2) * 16 + k];
            float h3 = sH16[(rbase + 3) * 16 + k];
            a0.x += h0 * w.x; a0.y += h0 * w.y; a0.z += h0 * w.z; a0.w += h0 * w.w;
            a1.x += h1v * w.x; a1.y += h1v * w.y; a1.z += h1v * w.z; a1.w += h1v * w.w;
            a2.x += h2 * w.x; a2.y += h2 * w.y; a2.z += h2 * w.z; a2.w += h2 * w.w;
            a3.x += h3 * w.x; a3.y += h3 * w.y; a3.z += h3 * w.z; a3.w += h3 * w.w;
        }
        float4 bb = *(const float4*)(b1 + c0);
        float4 accs[4] = {a0, a1, a2, a3};
        #pragma unroll
        for (int rr = 0; rr < 4; rr++) {
            float4 v = accs[rr];
            int r = rbase + rr;
            sH64[r * 65 + c0 + 0] = fmaxf(v.x + bb.x, 0.f);
            sH64[r * 65 + c0 + 1] = fmaxf(v.y + bb.y, 0.f);
            sH64[r * 65 + c0 + 2] = fmaxf(v.z + bb.z, 0.f);
            sH64[r * 65 + c0 + 3] = fmaxf(v.w + bb.w, 0.f);
        }
    }
    __syncthreads();                 // mm1 done reading sW(W1)
    for (int i = t * 4; i < 4096; i += 256 * 4)
        *(float4*)(sW + i) = *(const float4*)(W2 + i);
    __syncthreads();
    // mm64: hwba = bf16(dinv * (h1 @ W2))
    {
        float4 a0 = {0,0,0,0}, a1 = {0,0,0,0}, a2 = {0,0,0,0}, a3 = {0,0,0,0};
        for (int k = 0; k < 64; k++) {
            float4 w = *(const float4*)(sW + k * 64 + c0);
            float h0 = sH64[(rbase + 0) * 65 + k];
            float h1v = sH64[(rbase + 1) * 65 + k];
            float h2 = sH64[(rbase + 2) * 65 + k];
            float h3 = sH64[(rbase + 3) * 65 + k];
            a0.x += h0 * w.x; a0.y += h0 * w.y; a0.z += h0 * w.z; a0.w += h0 * w.w;
            a1.x += h1v * w.x; a1.y += h1v * w.y; a1.z += h1v * w.z; a1.w += h1v * w.w;
            a2.x += h2 * w.x; a2.y += h2 * w.y; a2.z += h2 * w.z; a2.w += h2 * w.w;
            a3.x += h3 * w.x; a3.y += h3 * w.y; a3.z += h3 * w.z; a3.w += h3 * w.w;
        }
        float4 accs[4] = {a0, a1, a2, a3};
        for (int rr = 0; rr < 4; rr++) {
            int node = node0 + rbase + rr;
            if (node >= N) break;
            float di = dinv[node];
            float4 v = accs[rr];
            ushort4 o;
            o.x = f2bf(v.x * di); o.y = f2bf(v.y * di);
            o.z = f2bf(v.z * di); o.w = f2bf(v.w * di);
            *(ushort4*)(hwba + (size_t)node * 64 + c0) = o;
        }
    }
}

// ================= fused layer2-gather (b2) + layer3-matmul (W3) =================
// 512 threads, 64 nodes per block. h2 never leaves LDS. Reads hwba, writes hwbb.

__global__ __launch_bounds__(512) void g2l3(
        const int* __restrict__ row_start, const int* __restrict__ row_cntp,
        const u16* __restrict__ csr2, const u16* __restrict__ hwba,
        const float* __restrict__ dinv, const float* __restrict__ b2,
        const float* __restrict__ W3,
        u16* __restrict__ hwbb, int N) {
    __shared__ float sW[64 * 64];
    __shared__ float sH64[64 * 65];      // h2
    int t = threadIdx.x;
    int node0 = blockIdx.x * 64;
    {
        int nl = t >> 3;                 // 0..63 node slot
        int node = node0 + nl;
        int c0 = (t & 7) * 8;            // this lane's 8 channels
        float acc[8] = {0.f,0.f,0.f,0.f,0.f,0.f,0.f,0.f};
        if (node < N) {
            uint4 sv = *(const uint4*)(hwba + (size_t)node * 64 + c0);
            bf8_add(acc, sv);
            int i0 = row_start[node], iE = i0 + row_cntp[node];
            for (int i = i0; i < iE; i += 8) {
                uint4 ev = *(const uint4*)(csr2 + i);
                int s0 = ev.x & 0xffff, s1 = ev.x >> 16;
                int s2 = ev.y & 0xffff, s3 = ev.y >> 16;
                int s4 = ev.z & 0xffff, s5 = ev.z >> 16;
                int s6 = ev.w & 0xffff, s7 = ev.w >> 16;
                uint4 u0 = *(const uint4*)(hwba + (size_t)s0 * 64 + c0);
                uint4 u1 = *(const uint4*)(hwba + (size_t)s1 * 64 + c0);
                uint4 u2 = *(const uint4*)(hwba + (size_t)s2 * 64 + c0);
                uint4 u3 = *(const uint4*)(hwba + (size_t)s3 * 64 + c0);
                uint4 u4 = *(const uint4*)(hwba + (size_t)s4 * 64 + c0);
                uint4 u5 = *(const uint4*)(hwba + (size_t)s5 * 64 + c0);
                uint4 u6 = *(const uint4*)(hwba + (size_t)s6 * 64 + c0);
                uint4 u7 = *(const uint4*)(hwba + (size_t)s7 * 64 + c0);
                bf8_add(acc, u0); bf8_add(acc, u1); bf8_add(acc, u2); bf8_add(acc, u3);
                bf8_add(acc, u4); bf8_add(acc, u5); bf8_add(acc, u6); bf8_add(acc, u7);
            }
            float di = dinv[node];
            const float4 bb0 = *(const float4*)(b2 + c0);
            const float4 bb1 = *(const float4*)(b2 + c0 + 4);
            acc[0] = fmaxf(acc[0]*di + bb0.x, 0.f); acc[1] = fmaxf(acc[1]*di + bb0.y, 0.f);
            acc[2] = fmaxf(acc[2]*di + bb0.z, 0.f); acc[3] = fmaxf(acc[3]*di + bb0.w, 0.f);
            acc[4] = fmaxf(acc[4]*di + bb1.x, 0.f); acc[5] = fmaxf(acc[5]*di + bb1.y, 0.f);
            acc[6] = fmaxf(acc[6]*di + bb1.z, 0.f); acc[7] = fmaxf(acc[7]*di + bb1.w, 0.f);
        }
        #pragma unroll
        for (int j = 0; j < 8; j++) sH64[nl * 65 + c0 + j] = acc[j];
    }
    for (int i = t * 4; i < 4096; i += 512 * 4)
        *(float4*)(sW + i) = *(const float4*)(W3 + i);
    __syncthreads();
    // mm64: hwbb = bf16(dinv * (h2 @ W3)); 512 threads -> 2 rows x 4 cols each
    {
        int c0 = (t & 15) * 4;
        int r0 = (t >> 4) * 2;
        float4 a0 = {0,0,0,0}, a1 = {0,0,0,0};
        for (int k = 0; k < 64; k++) {
            float4 w = *(const float4*)(sW + k * 64 + c0);
            float h0 = sH64[(r0 + 0) * 65 + k];
            float h1v = sH64[(r0 + 1) * 65 + k];
            a0.x += h0 * w.x; a0.y += h0 * w.y; a0.z += h0 * w.z; a0.w += h0 * w.w;
            a1.x += h1v * w.x; a1.y += h1v * w.y; a1.z += h1v * w.z; a1.w += h1v * w.w;
        }
        float4 accs[2] = {a0, a1};
        for (int rr = 0; rr < 2; rr++) {
            int node = node0 + r0 + rr;
            if (node >= N) break;
            float di = dinv[node];
            float4 v = accs[rr];
            ushort4 o;
            o.x = f2bf(v.x * di); o.y = f2bf(v.y * di);
            o.z = f2bf(v.z * di); o.w = f2bf(v.w * di);
            *(ushort4*)(hwbb + (size_t)node * 64 + c0) = o;
        }
    }
}

// ================= layer3 gather (b3) -> h3 + global sum =================

__global__ __launch_bounds__(256) void gather_b3(
        const int* __restrict__ row_start, const int* __restrict__ row_cntp,
        const u16* __restrict__ csr2, const u16* __restrict__ hwbb,
        const float* __restrict__ dinv, const float* __restrict__ b,
        float* __restrict__ out, float* __restrict__ gsum, int N) {
    int t = threadIdx.x;
    int nl = t >> 3;                       // 0..31 node slot in block
    int node = blockIdx.x * 32 + nl;
    int c0 = (t & 7) * 8;
    float acc[8] = {0.f,0.f,0.f,0.f,0.f,0.f,0.f,0.f};
    if (node < N) {
        uint4 sv = *(const uint4*)(hwbb + (size_t)node * 64 + c0);
        bf8_add(acc, sv);
        int i0 = row_start[node], iE = i0 + row_cntp[node];
        for (int i = i0; i < iE; i += 8) {
            uint4 ev = *(const uint4*)(csr2 + i);
            int s0 = ev.x & 0xffff, s1 = ev.x >> 16;
            int s2 = ev.y & 0xffff, s3 = ev.y >> 16;
            int s4 = ev.z & 0xffff, s5 = ev.z >> 16;
            int s6 = ev.w & 0xffff, s7 = ev.w >> 16;
            uint4 u0 = *(const uint4*)(hwbb + (size_t)s0 * 64 + c0);
            uint4 u1 = *(const uint4*)(hwbb + (size_t)s1 * 64 + c0);
            uint4 u2 = *(const uint4*)(hwbb + (size_t)s2 * 64 + c0);
            uint4 u3 = *(const uint4*)(hwbb + (size_t)s3 * 64 + c0);
            uint4 u4 = *(const uint4*)(hwbb + (size_t)s4 * 64 + c0);
            uint4 u5 = *(const uint4*)(hwbb + (size_t)s5 * 64 + c0);
            uint4 u6 = *(const uint4*)(hwbb + (size_t)s6 * 64 + c0);
            uint4 u7 = *(const uint4*)(hwbb + (size_t)s7 * 64 + c0);
            bf8_add(acc, u0); bf8_add(acc, u1); bf8_add(acc, u2); bf8_add(acc, u3);
            bf8_add(acc, u4); bf8_add(acc, u5); bf8_add(acc, u6); bf8_add(acc, u7);
        }
        float di = dinv[node];
        const float4 bb0 = *(const float4*)(b + c0);
        const float4 bb1 = *(const float4*)(b + c0 + 4);
        float4 o0, o1;
        o0.x = fmaxf(acc[0]*di + bb0.x, 0.f); o0.y = fmaxf(acc[1]*di + bb0.y, 0.f);
        o0.z = fmaxf(acc[2]*di + bb0.z, 0.f); o0.w = fmaxf(acc[3]*di + bb0.w, 0.f);
        o1.x = fmaxf(acc[4]*di + bb1.x, 0.f); o1.y = fmaxf(acc[5]*di + bb1.y, 0.f);
        o1.z = fmaxf(acc[6]*di + bb1.z, 0.f); o1.w = fmaxf(acc[7]*di + bb1.w, 0.f);
        *(float4*)(out + (size_t)node * 64 + c0)     = o0;
        *(float4*)(out + (size_t)node * 64 + c0 + 4) = o1;
        acc[0]=o0.x; acc[1]=o0.y; acc[2]=o0.z; acc[3]=o0.w;
        acc[4]=o1.x; acc[5]=o1.y; acc[6]=o1.z; acc[7]=o1.w;
    }
    __shared__ float red[32 * 64];
    #pragma unroll
    for (int j = 0; j < 8; j++) red[nl * 64 + c0 + j] = acc[j];
    __syncthreads();
    if (t < 64) {
        float s = 0.f;
        #pragma unroll 8
        for (int k = 0; k < 32; k++) s += red[k * 64 + t];
        atomicAdd(&gsum[t], s);
    }
}

// ================= head =================

__global__ __launch_bounds__(256) void final_kernel(
        const float* __restrict__ h3, const int* __restrict__ sheet_idx,
        const float* __restrict__ sheet_feat, const float* __restrict__ g_sum,
        const float* __restrict__ gW1, const float* __restrict__ gb1,
        const float* __restrict__ gW2, const float* __restrict__ gb2,
        const float* __restrict__ fW,  const float* __restrict__ fb,
        const float* __restrict__ qW1, const float* __restrict__ qb1,
        const float* __restrict__ qW2, const float* __restrict__ qb2,
        float* __restrict__ out, int N, int L) {
    int s = blockIdx.x, t = threadIdx.x;
    __shared__ float red[256];
    __shared__ float semb[64];
    __shared__ float geoh[64];
    __shared__ float geo[64];
    __shared__ float hq[128];
    int c = t & 63, jg = t >> 6;
    float acc = 0.0f;
    for (int j = jg; j < L; j += 4) {
        int node = sheet_idx[s * L + j];
        acc += h3[(size_t)node * 64 + c];
    }
    red[t] = acc;
    __syncthreads();
    if (t < 64) {
        semb[t] = (red[t] + red[t + 64] + red[t + 128] + red[t + 192]) / (float)L;
        hq[64 + t] = g_sum[t] / (float)N;
        float a = gb1[t];
        #pragma unroll
        for (int k = 0; k < FEAT; k++) a += sheet_feat[s * FEAT + k] * gW1[k * 64 + t];
        geoh[t] = fmaxf(a, 0.0f);
    }
    __syncthreads();
    if (t < 64) {
        float a = gb2[t];
        for (int k = 0; k < 64; k++) a += geoh[k] * gW2[k * 64 + t];
        geo[t] = a;
    }
    __syncthreads();
    if (t < 64) {
        float a = fb[t];
        for (int k = 0; k < 64; k++) a += semb[k] * fW[k * 64 + t];
        for (int k = 0; k < 64; k++) a += geo[k]  * fW[(64 + k) * 64 + t];
        hq[t] = fmaxf(a, 0.0f);
    }
    __syncthreads();
    float q = 0.0f;
    if (t < 64) {
        float a = qb1[t];
        for (int k = 0; k < 128; k++) a += hq[k] * qW1[k * 64 + t];
        a = fmaxf(a, 0.0f);
        q = a * qW2[t];
        for (int off = 32; off > 0; off >>= 1) q += __shfl_down(q, off, 64);
        if (t == 0) out[s] = q + qb2[0];
    }
}

extern "C" void kernel_launch(void* const* d_in, const int* in_sizes, int n_in,
                              void* d_out, int out_size, void* d_ws, size_t ws_size,
                              hipStream_t stream) {
    const float* x          = (const float*)d_in[0];
    const int*   edge       = (const int*)d_in[1];
    const int*   sheet_idx  = (const int*)d_in[3];
    const float* sheet_feat = (const float*)d_in[4];
    const float* W1 = (const float*)d_in[5];  const float* b1 = (const float*)d_in[6];
    const float* W2 = (const float*)d_in[7];  const float* b2 = (const float*)d_in[8];
    const float* W3 = (const float*)d_in[9];  const float* b3 = (const float*)d_in[10];
    const float* gW1 = (const float*)d_in[11]; const float* gb1 = (const float*)d_in[12];
    const float* gW2 = (const float*)d_in[13]; const float* gb2 = (const float*)d_in[14];
    const float* fW  = (const float*)d_in[15]; const float* fb  = (const float*)d_in[16];
    const float* qW1 = (const float*)d_in[17]; const float* qb1 = (const float*)d_in[18];
    const float* qW2 = (const float*)d_in[19]; const float* qb2 = (const float*)d_in[20];
    float* out = (float*)d_out;

    int N = in_sizes[2];            // 50000
    int E = in_sizes[1] / 2;        // 800000
    int S = in_sizes[4] / FEAT;     // 256
    int L = in_sizes[3] / S;        // 128

    int nbuckets = (N + 255) / 256;     // 196 (u16 src requires N < 65535)
    int nchunks  = (E + 4095) / 4096;   // 196

    char* p = (char*)d_ws;
    unsigned* tmp  = (unsigned*)p;             p += (size_t)nbuckets * MAXSEG * 4;
    u16* csr2      = (u16*)p;                  p += (size_t)nbuckets * MAXSEG * 2;
    float* hf      = (float*)p;                p += (size_t)N * 64 * 4;      // h3 only
    u16* hwba      = (u16*)p;                  p += (size_t)(N + 1) * 64 * 2; // layer2 matmul out
    u16* hwbb      = (u16*)p;                  p += (size_t)(N + 1) * 64 * 2; // layer3 matmul out
    u16* xp        = (u16*)p;                  p += (size_t)(N + 1) * 16 * 2;
    int* row_start = (int*)p;                  p += (size_t)N * 4;
    int* row_cntp  = (int*)p;                  p += (size_t)N * 4;
    float* dinv    = (float*)p;                p += (size_t)N * 4;
    int* gcnt      = (int*)p;                  p += 256 * 4;
    float* gsum    = (float*)p;                p += 64 * 4;

    hipMemsetAsync(gcnt, 0, 256 * 4 + 64 * 4, stream);   // gcnt + gsum (adjacent)

    const int* src = edge;
    const int* dst = edge + E;

    int gMM = (N + 63) / 64;            // 782
    int gGB = (N + 31) / 32;            // 1563

    bin_kernel<<<nchunks, 1024, 0, stream>>>(src, dst, gcnt, tmp, hwba, hwbb, xp, E, N);
    csr_build<<<nbuckets, 1024, 0, stream>>>(tmp, gcnt, csr2, row_start, row_cntp, dinv, x, xp, N);

    l1l2<<<gMM, 256, 0, stream>>>(row_start, row_cntp, csr2, xp, dinv, W1, b1, W2, hwba, N);
    g2l3<<<gMM, 512, 0, stream>>>(row_start, row_cntp, csr2, hwba, dinv, b2, W3, hwbb, N);
    gather_b3<<<gGB, 256, 0, stream>>>(row_start, row_cntp, csr2, hwbb, dinv, b3, hf, gsum, N);

    final_kernel<<<S, 256, 0, stream>>>(hf, sheet_idx, sheet_feat, gsum,
                                        gW1, gb1, gW2, gb2, fW, fb,
                                        qW1, qb1, qW2, qb2, out, N, L);
}

// Round 6
// 218.994 us; speedup vs baseline: 1.1559x; 1.1083x over previous
//
#include <hip/hip_runtime.h>

#define HID 64
#define FEAT 10
#define MAXSEG 8192        // fixed per-bucket segment (mean fill 4081, 64 sigma margin)

typedef unsigned short u16;

// ---------- helpers ----------
__device__ __forceinline__ u16 f2bf(float f) {            // fp32 -> bf16 RNE
    unsigned u = __float_as_uint(f);
    unsigned r = (u + 0x7fffu + ((u >> 16) & 1u)) >> 16;
    return (u16)r;
}
__device__ __forceinline__ void bf8_add(float* acc, uint4 u) {
    acc[0] += __uint_as_float(u.x << 16);
    acc[1] += __uint_as_float(u.x & 0xffff0000u);
    acc[2] += __uint_as_float(u.y << 16);
    acc[3] += __uint_as_float(u.y & 0xffff0000u);
    acc[4] += __uint_as_float(u.z << 16);
    acc[5] += __uint_as_float(u.z & 0xffff0000u);
    acc[6] += __uint_as_float(u.w << 16);
    acc[7] += __uint_as_float(u.w & 0xffff0000u);
}

// ================= CSR build (2 kernels) =================

// One pass over edges: LDS histogram -> global range reservation -> emit from registers.
// Bucket b owns tmp[b*MAXSEG .. b*MAXSEG+cnt). Also zeroes sentinel rows (block 0).
__global__ __launch_bounds__(1024) void bin_kernel(
        const int* __restrict__ src, const int* __restrict__ dst,
        int* __restrict__ gcnt, unsigned* __restrict__ tmp,
        u16* __restrict__ hwba, u16* __restrict__ hwbb, u16* __restrict__ xp,
        int E, int N) {
    __shared__ int h[256];           // histogram, then current-slot cursors
    int t = threadIdx.x, c = blockIdx.x;
    if (t < 256) h[t] = 0;
    __syncthreads();
    int b0 = c * 4096;
    unsigned pk[4]; int bk[4];
    #pragma unroll
    for (int j = 0; j < 4; j++) {
        int e = b0 + t + j * 1024;
        if (e < E) {
            int s = src[e], d = dst[e];
            pk[j] = ((unsigned)(d & 255) << 16) | (unsigned)s;
            bk[j] = d >> 8;
            atomicAdd(&h[bk[j]], 1);
        } else bk[j] = -1;
    }
    __syncthreads();
    if (t < 256) {
        int v = h[t];
        int resv = v ? atomicAdd(&gcnt[t], v) : 0;
        h[t] = t * MAXSEG + resv;    // cursor = fixed bucket base + reserved offset
    }
    __syncthreads();
    #pragma unroll
    for (int j = 0; j < 4; j++) {
        if (bk[j] >= 0) {
            int slot = atomicAdd(&h[bk[j]], 1);
            tmp[slot] = pk[j];
        }
    }
    if (c == 0) {                    // sentinel rows (node N): zero
        if (t < 64)       hwba[(size_t)N * 64 + t] = 0;
        else if (t < 128) hwbb[(size_t)N * 64 + (t - 64)] = 0;
        else if (t < 144) xp[(size_t)N * 16 + (t - 128)] = 0;
    }
}

// per-bucket node-sort into padded u16 CSR + row metadata + dinv + pad_x
__global__ __launch_bounds__(1024) void csr_build(
        const unsigned* __restrict__ tmp, const int* __restrict__ gcnt,
        u16* __restrict__ csr2,
        int* __restrict__ row_start, int* __restrict__ row_cntp,
        float* __restrict__ dinv,
        const float* __restrict__ x, u16* __restrict__ xp, int N) {
    __shared__ __align__(16) u16 staged[MAXSEG];
    __shared__ int cntL[256], padL[256], scanL[256], curL[256];
    __shared__ float sdinv[256];
    int b = blockIdx.x, t = threadIdx.x;          // 1024 threads
    if (t < 256) cntL[t] = 0;
    for (int i = t; i < MAXSEG; i += 1024) staged[i] = (u16)N;   // sentinel prefill
    __syncthreads();
    int segBase = b * MAXSEG, segLen = gcnt[b];
    for (int i = t; i < segLen; i += 1024)
        atomicAdd(&cntL[tmp[segBase + i] >> 16], 1);
    __syncthreads();
    if (t < 256) { padL[t] = (cntL[t] + 7) & ~7; scanL[t] = padL[t]; }
    __syncthreads();
    for (int off = 1; off < 256; off <<= 1) {
        int a = (t < 256) ? scanL[t] : 0;
        int s = (t >= off && t < 256) ? scanL[t - off] : 0;
        __syncthreads();
        if (t < 256) scanL[t] = a + s;
        __syncthreads();
    }
    if (t < 256) {
        int excl = scanL[t] - padL[t];
        curL[t] = excl;
        float dv = rsqrtf((float)cntL[t] + 1.0f);
        sdinv[t] = dv;
        int node = b * 256 + t;
        if (node < N) {
            row_start[node] = b * MAXSEG + excl;
            row_cntp[node]  = padL[t];
            dinv[node]      = dv;
        }
    }
    __syncthreads();
    for (int i = t; i < segLen; i += 1024) {
        unsigned e = tmp[segBase + i];
        int idx = atomicAdd(&curL[e >> 16], 1);
        staged[idx] = (u16)(e & 0xffffu);
    }
    // pad_x for this bucket's 256 nodes (independent of staged[])
    for (int i = t; i < 256 * 16; i += 1024) {
        int nlc = i >> 4, cch = i & 15;
        int node = b * 256 + nlc;
        if (node < N)
            xp[(size_t)node * 16 + cch] =
                (cch < FEAT) ? f2bf(sdinv[nlc] * x[(size_t)node * FEAT + cch]) : (u16)0;
    }
    __syncthreads();
    ((uint4*)(csr2 + (size_t)b * MAXSEG))[t] = ((const uint4*)staged)[t];
}

// ================= fused layer1 (gather_x+mm1) + layer2-matmul (W2) =================
// 256 threads, 64 nodes per block. h1 never leaves LDS.

__global__ __launch_bounds__(256) void l1l2(
        const int* __restrict__ row_start, const int* __restrict__ row_cntp,
        const u16* __restrict__ csr2, const u16* __restrict__ xp,
        const float* __restrict__ dinv,
        const float* __restrict__ W1, const float* __restrict__ b1,
        const float* __restrict__ W2,
        u16* __restrict__ hwba, int N) {
    __shared__ float sW[64 * 64];        // W1 (first 640) then W2
    __shared__ float sH16[64 * 16];      // scaled aggregate of x
    __shared__ float sH64[64 * 65];      // h1
    int t = threadIdx.x;
    int node0 = blockIdx.x * 64;
    for (int i = t; i < FEAT * 64; i += 256) sW[i] = W1[i];
    if (t < 128) {
        int nl = t >> 1;
        int node = node0 + nl;
        int c0 = (t & 1) * 8;
        float acc[8] = {0.f,0.f,0.f,0.f,0.f,0.f,0.f,0.f};
        if (node < N) {
            uint4 sv = *(const uint4*)(xp + (size_t)node * 16 + c0);
            bf8_add(acc, sv);
            int i0 = row_start[node], iE = i0 + row_cntp[node];
            for (int i = i0; i < iE; i += 8) {
                uint4 ev = *(const uint4*)(csr2 + i);
                int s0 = ev.x & 0xffff, s1 = ev.x >> 16;
                int s2 = ev.y & 0xffff, s3 = ev.y >> 16;
                int s4 = ev.z & 0xffff, s5 = ev.z >> 16;
                int s6 = ev.w & 0xffff, s7 = ev.w >> 16;
                uint4 u0 = *(const uint4*)(xp + (size_t)s0 * 16 + c0);
                uint4 u1 = *(const uint4*)(xp + (size_t)s1 * 16 + c0);
                uint4 u2 = *(const uint4*)(xp + (size_t)s2 * 16 + c0);
                uint4 u3 = *(const uint4*)(xp + (size_t)s3 * 16 + c0);
                uint4 u4 = *(const uint4*)(xp + (size_t)s4 * 16 + c0);
                uint4 u5 = *(const uint4*)(xp + (size_t)s5 * 16 + c0);
                uint4 u6 = *(const uint4*)(xp + (size_t)s6 * 16 + c0);
                uint4 u7 = *(const uint4*)(xp + (size_t)s7 * 16 + c0);
                bf8_add(acc, u0); bf8_add(acc, u1); bf8_add(acc, u2); bf8_add(acc, u3);
                bf8_add(acc, u4); bf8_add(acc, u5); bf8_add(acc, u6); bf8_add(acc, u7);
            }
            float di = dinv[node];
            #pragma unroll
            for (int j = 0; j < 8; j++) acc[j] *= di;
        }
        #pragma unroll
        for (int j = 0; j < 8; j++) sH16[nl * 16 + c0 + j] = acc[j];
    }
    __syncthreads();
    // mm1: h1 = relu(agg @ W1 + b1) -> sH64
    int c0 = (t & 15) * 4;
    int rbase = (t >> 4) * 4;
    {
        float4 a0 = {0,0,0,0}, a1 = {0,0,0,0}, a2 = {0,0,0,0}, a3 = {0,0,0,0};
        for (int k = 0; k < FEAT; k++) {
            float4 w = *(const float4*)(sW + k * 64 + c0);
            float h0 = sH16[(rbase + 0) * 16 + k];
            float h1v = sH16[(rbase + 1) * 16 + k];
            float h2 = sH16[(rbase + 2) * 16 + k];
            float h3 = sH16[(rbase + 3) * 16 + k];
            a0.x += h0 * w.x; a0.y += h0 * w.y; a0.z += h0 * w.z; a0.w += h0 * w.w;
            a1.x += h1v * w.x; a1.y += h1v * w.y; a1.z += h1v * w.z; a1.w += h1v * w.w;
            a2.x += h2 * w.x; a2.y += h2 * w.y; a2.z += h2 * w.z; a2.w += h2 * w.w;
            a3.x += h3 * w.x; a3.y += h3 * w.y; a3.z += h3 * w.z; a3.w += h3 * w.w;
        }
        float4 bb = *(const float4*)(b1 + c0);
        float4 accs[4] = {a0, a1, a2, a3};
        #pragma unroll
        for (int rr = 0; rr < 4; rr++) {
            float4 v = accs[rr];
            int r = rbase + rr;
            sH64[r * 65 + c0 + 0] = fmaxf(v.x + bb.x, 0.f);
            sH64[r * 65 + c0 + 1] = fmaxf(v.y + bb.y, 0.f);
            sH64[r * 65 + c0 + 2] = fmaxf(v.z + bb.z, 0.f);
            sH64[r * 65 + c0 + 3] = fmaxf(v.w + bb.w, 0.f);
        }
    }
    __syncthreads();                 // mm1 done reading sW(W1)
    for (int i = t * 4; i < 4096; i += 256 * 4)
        *(float4*)(sW + i) = *(const float4*)(W2 + i);
    __syncthreads();
    // mm64: hwba = bf16(dinv * (h1 @ W2))
    {
        float4 a0 = {0,0,0,0}, a1 = {0,0,0,0}, a2 = {0,0,0,0}, a3 = {0,0,0,0};
        for (int k = 0; k < 64; k++) {
            float4 w = *(const float4*)(sW + k * 64 + c0);
            float h0 = sH64[(rbase + 0) * 65 + k];
            float h1v = sH64[(rbase + 1) * 65 + k];
            float h2 = sH64[(rbase + 2) * 65 + k];
            float h3 = sH64[(rbase + 3) * 65 + k];
            a0.x += h0 * w.x; a0.y += h0 * w.y; a0.z += h0 * w.z; a0.w += h0 * w.w;
            a1.x += h1v * w.x; a1.y += h1v * w.y; a1.z += h1v * w.z; a1.w += h1v * w.w;
            a2.x += h2 * w.x; a2.y += h2 * w.y; a2.z += h2 * w.z; a2.w += h2 * w.w;
            a3.x += h3 * w.x; a3.y += h3 * w.y; a3.z += h3 * w.z; a3.w += h3 * w.w;
        }
        float4 accs[4] = {a0, a1, a2, a3};
        for (int rr = 0; rr < 4; rr++) {
            int node = node0 + rbase + rr;
            if (node >= N) break;
            float di = dinv[node];
            float4 v = accs[rr];
            ushort4 o;
            o.x = f2bf(v.x * di); o.y = f2bf(v.y * di);
            o.z = f2bf(v.z * di); o.w = f2bf(v.w * di);
            *(ushort4*)(hwba + (size_t)node * 64 + c0) = o;
        }
    }
}

// ================= fused layer2-gather (b2) + layer3-matmul (W3) =================
// 512 threads, 64 nodes per block. h2 never leaves LDS. Reads hwba, writes hwbb.

__global__ __launch_bounds__(512) void g2l3(
        const int* __restrict__ row_start, const int* __restrict__ row_cntp,
        const u16* __restrict__ csr2, const u16* __restrict__ hwba,
        const float* __restrict__ dinv, const float* __restrict__ b2,
        const float* __restrict__ W3,
        u16* __restrict__ hwbb, int N) {
    __shared__ float sW[64 * 64];
    __shared__ float sH64[64 * 65];      // h2
    int t = threadIdx.x;
    int node0 = blockIdx.x * 64;
    {
        int nl = t >> 3;                 // 0..63 node slot
        int node = node0 + nl;
        int c0 = (t & 7) * 8;            // this lane's 8 channels
        float acc[8] = {0.f,0.f,0.f,0.f,0.f,0.f,0.f,0.f};
        if (node < N) {
            uint4 sv = *(const uint4*)(hwba + (size_t)node * 64 + c0);
            bf8_add(acc, sv);
            int i0 = row_start[node], iE = i0 + row_cntp[node];
            for (int i = i0; i < iE; i += 8) {
                uint4 ev = *(const uint4*)(csr2 + i);
                int s0 = ev.x & 0xffff, s1 = ev.x >> 16;
                int s2 = ev.y & 0xffff, s3 = ev.y >> 16;
                int s4 = ev.z & 0xffff, s5 = ev.z >> 16;
                int s6 = ev.w & 0xffff, s7 = ev.w >> 16;
                uint4 u0 = *(const uint4*)(hwba + (size_t)s0 * 64 + c0);
                uint4 u1 = *(const uint4*)(hwba + (size_t)s1 * 64 + c0);
                uint4 u2 = *(const uint4*)(hwba + (size_t)s2 * 64 + c0);
                uint4 u3 = *(const uint4*)(hwba + (size_t)s3 * 64 + c0);
                uint4 u4 = *(const uint4*)(hwba + (size_t)s4 * 64 + c0);
                uint4 u5 = *(const uint4*)(hwba + (size_t)s5 * 64 + c0);
                uint4 u6 = *(const uint4*)(hwba + (size_t)s6 * 64 + c0);
                uint4 u7 = *(const uint4*)(hwba + (size_t)s7 * 64 + c0);
                bf8_add(acc, u0); bf8_add(acc, u1); bf8_add(acc, u2); bf8_add(acc, u3);
                bf8_add(acc, u4); bf8_add(acc, u5); bf8_add(acc, u6); bf8_add(acc, u7);
            }
            float di = dinv[node];
            const float4 bb0 = *(const float4*)(b2 + c0);
            const float4 bb1 = *(const float4*)(b2 + c0 + 4);
            acc[0] = fmaxf(acc[0]*di + bb0.x, 0.f); acc[1] = fmaxf(acc[1]*di + bb0.y, 0.f);
            acc[2] = fmaxf(acc[2]*di + bb0.z, 0.f); acc[3] = fmaxf(acc[3]*di + bb0.w, 0.f);
            acc[4] = fmaxf(acc[4]*di + bb1.x, 0.f); acc[5] = fmaxf(acc[5]*di + bb1.y, 0.f);
            acc[6] = fmaxf(acc[6]*di + bb1.z, 0.f); acc[7] = fmaxf(acc[7]*di + bb1.w, 0.f);
        }
        #pragma unroll
        for (int j = 0; j < 8; j++) sH64[nl * 65 + c0 + j] = acc[j];
    }
    for (int i = t * 4; i < 4096; i += 512 * 4)
        *(float4*)(sW + i) = *(const float4*)(W3 + i);
    __syncthreads();
    // mm64: hwbb = bf16(dinv * (h2 @ W3)); 512 threads -> 2 rows x 4 cols each
    {
        int c0 = (t & 15) * 4;
        int r0 = (t >> 4) * 2;
        float4 a0 = {0,0,0,0}, a1 = {0,0,0,0};
        for (int k = 0; k < 64; k++) {
            float4 w = *(const float4*)(sW + k * 64 + c0);
            float h0 = sH64[(r0 + 0) * 65 + k];
            float h1v = sH64[(r0 + 1) * 65 + k];
            a0.x += h0 * w.x; a0.y += h0 * w.y; a0.z += h0 * w.z; a0.w += h0 * w.w;
            a1.x += h1v * w.x; a1.y += h1v * w.y; a1.z += h1v * w.z; a1.w += h1v * w.w;
        }
        float4 accs[2] = {a0, a1};
        for (int rr = 0; rr < 2; rr++) {
            int node = node0 + r0 + rr;
            if (node >= N) break;
            float di = dinv[node];
            float4 v = accs[rr];
            ushort4 o;
            o.x = f2bf(v.x * di); o.y = f2bf(v.y * di);
            o.z = f2bf(v.z * di); o.w = f2bf(v.w * di);
            *(ushort4*)(hwbb + (size_t)node * 64 + c0) = o;
        }
    }
}

// ================= layer3 gather (b3) -> h3 + per-block partial sums =================

__global__ __launch_bounds__(256) void gather_b3(
        const int* __restrict__ row_start, const int* __restrict__ row_cntp,
        const u16* __restrict__ csr2, const u16* __restrict__ hwbb,
        const float* __restrict__ dinv, const float* __restrict__ b,
        float* __restrict__ out, float* __restrict__ part, int N) {
    int t = threadIdx.x;
    int nl = t >> 3;                       // 0..31 node slot in block
    int node = blockIdx.x * 32 + nl;
    int c0 = (t & 7) * 8;
    float acc[8] = {0.f,0.f,0.f,0.f,0.f,0.f,0.f,0.f};
    if (node < N) {
        uint4 sv = *(const uint4*)(hwbb + (size_t)node * 64 + c0);
        bf8_add(acc, sv);
        int i0 = row_start[node], iE = i0 + row_cntp[node];
        for (int i = i0; i < iE; i += 8) {
            uint4 ev = *(const uint4*)(csr2 + i);
            int s0 = ev.x & 0xffff, s1 = ev.x >> 16;
            int s2 = ev.y & 0xffff, s3 = ev.y >> 16;
            int s4 = ev.z & 0xffff, s5 = ev.z >> 16;
            int s6 = ev.w & 0xffff, s7 = ev.w >> 16;
            uint4 u0 = *(const uint4*)(hwbb + (size_t)s0 * 64 + c0);
            uint4 u1 = *(const uint4*)(hwbb + (size_t)s1 * 64 + c0);
            uint4 u2 = *(const uint4*)(hwbb + (size_t)s2 * 64 + c0);
            uint4 u3 = *(const uint4*)(hwbb + (size_t)s3 * 64 + c0);
            uint4 u4 = *(const uint4*)(hwbb + (size_t)s4 * 64 + c0);
            uint4 u5 = *(const uint4*)(hwbb + (size_t)s5 * 64 + c0);
            uint4 u6 = *(const uint4*)(hwbb + (size_t)s6 * 64 + c0);
            uint4 u7 = *(const uint4*)(hwbb + (size_t)s7 * 64 + c0);
            bf8_add(acc, u0); bf8_add(acc, u1); bf8_add(acc, u2); bf8_add(acc, u3);
            bf8_add(acc, u4); bf8_add(acc, u5); bf8_add(acc, u6); bf8_add(acc, u7);
        }
        float di = dinv[node];
        const float4 bb0 = *(const float4*)(b + c0);
        const float4 bb1 = *(const float4*)(b + c0 + 4);
        float4 o0, o1;
        o0.x = fmaxf(acc[0]*di + bb0.x, 0.f); o0.y = fmaxf(acc[1]*di + bb0.y, 0.f);
        o0.z = fmaxf(acc[2]*di + bb0.z, 0.f); o0.w = fmaxf(acc[3]*di + bb0.w, 0.f);
        o1.x = fmaxf(acc[4]*di + bb1.x, 0.f); o1.y = fmaxf(acc[5]*di + bb1.y, 0.f);
        o1.z = fmaxf(acc[6]*di + bb1.z, 0.f); o1.w = fmaxf(acc[7]*di + bb1.w, 0.f);
        *(float4*)(out + (size_t)node * 64 + c0)     = o0;
        *(float4*)(out + (size_t)node * 64 + c0 + 4) = o1;
        acc[0]=o0.x; acc[1]=o0.y; acc[2]=o0.z; acc[3]=o0.w;
        acc[4]=o1.x; acc[5]=o1.y; acc[6]=o1.z; acc[7]=o1.w;
    }
    __shared__ float red[32 * 64];
    #pragma unroll
    for (int j = 0; j < 8; j++) red[nl * 64 + c0 + j] = acc[j];
    __syncthreads();
    if (t < 64) {
        float s = 0.f;
        #pragma unroll 8
        for (int k = 0; k < 32; k++) s += red[k * 64 + t];
        part[(size_t)blockIdx.x * 64 + t] = s;    // plain store, no device-scope atomic storm
    }
}

// reduce 1563x64 block partials -> gsum[64]. One wave per channel.
__global__ __launch_bounds__(64) void gsum_reduce(const float* __restrict__ part,
                                                  float* __restrict__ gsum, int NB) {
    int c = blockIdx.x, t = threadIdx.x;
    float s = 0.f;
    for (int i = t; i < NB; i += 64) s += part[(size_t)i * 64 + c];
    for (int off = 32; off > 0; off >>= 1) s += __shfl_down(s, off, 64);
    if (t == 0) gsum[c] = s;
}

// ================= head =================

__global__ __launch_bounds__(256) void final_kernel(
        const float* __restrict__ h3, const int* __restrict__ sheet_idx,
        const float* __restrict__ sheet_feat, const float* __restrict__ g_sum,
        const float* __restrict__ gW1, const float* __restrict__ gb1,
        const float* __restrict__ gW2, const float* __restrict__ gb2,
        const float* __restrict__ fW,  const float* __restrict__ fb,
        const float* __restrict__ qW1, const float* __restrict__ qb1,
        const float* __restrict__ qW2, const float* __restrict__ qb2,
        float* __restrict__ out, int N, int L) {
    int s = blockIdx.x, t = threadIdx.x;
    __shared__ float red[256];
    __shared__ float semb[64];
    __shared__ float geoh[64];
    __shared__ float geo[64];
    __shared__ float hq[128];
    int c = t & 63, jg = t >> 6;
    float acc = 0.0f;
    for (int j = jg; j < L; j += 4) {
        int node = sheet_idx[s * L + j];
        acc += h3[(size_t)node * 64 + c];
    }
    red[t] = acc;
    __syncthreads();
    if (t < 64) {
        semb[t] = (red[t] + red[t + 64] + red[t + 128] + red[t + 192]) / (float)L;
        hq[64 + t] = g_sum[t] / (float)N;
        float a = gb1[t];
        #pragma unroll
        for (int k = 0; k < FEAT; k++) a += sheet_feat[s * FEAT + k] * gW1[k * 64 + t];
        geoh[t] = fmaxf(a, 0.0f);
    }
    __syncthreads();
    if (t < 64) {
        float a = gb2[t];
        for (int k = 0; k < 64; k++) a += geoh[k] * gW2[k * 64 + t];
        geo[t] = a;
    }
    __syncthreads();
    if (t < 64) {
        float a = fb[t];
        for (int k = 0; k < 64; k++) a += semb[k] * fW[k * 64 + t];
        for (int k = 0; k < 64; k++) a += geo[k]  * fW[(64 + k) * 64 + t];
        hq[t] = fmaxf(a, 0.0f);
    }
    __syncthreads();
    float q = 0.0f;
    if (t < 64) {
        float a = qb1[t];
        for (int k = 0; k < 128; k++) a += hq[k] * qW1[k * 64 + t];
        a = fmaxf(a, 0.0f);
        q = a * qW2[t];
        for (int off = 32; off > 0; off >>= 1) q += __shfl_down(q, off, 64);
        if (t == 0) out[s] = q + qb2[0];
    }
}

extern "C" void kernel_launch(void* const* d_in, const int* in_sizes, int n_in,
                              void* d_out, int out_size, void* d_ws, size_t ws_size,
                              hipStream_t stream) {
    const float* x          = (const float*)d_in[0];
    const int*   edge       = (const int*)d_in[1];
    const int*   sheet_idx  = (const int*)d_in[3];
    const float* sheet_feat = (const float*)d_in[4];
    const float* W1 = (const float*)d_in[5];  const float* b1 = (const float*)d_in[6];
    const float* W2 = (const float*)d_in[7];  const float* b2 = (const float*)d_in[8];
    const float* W3 = (const float*)d_in[9];  const float* b3 = (const float*)d_in[10];
    const float* gW1 = (const float*)d_in[11]; const float* gb1 = (const float*)d_in[12];
    const float* gW2 = (const float*)d_in[13]; const float* gb2 = (const float*)d_in[14];
    const float* fW  = (const float*)d_in[15]; const float* fb  = (const float*)d_in[16];
    const float* qW1 = (const float*)d_in[17]; const float* qb1 = (const float*)d_in[18];
    const float* qW2 = (const float*)d_in[19]; const float* qb2 = (const float*)d_in[20];
    float* out = (float*)d_out;

    int N = in_sizes[2];            // 50000
    int E = in_sizes[1] / 2;        // 800000
    int S = in_sizes[4] / FEAT;     // 256
    int L = in_sizes[3] / S;        // 128

    int nbuckets = (N + 255) / 256;     // 196 (u16 src requires N < 65535)
    int nchunks  = (E + 4095) / 4096;   // 196

    int gMM = (N + 63) / 64;            // 782
    int gGB = (N + 31) / 32;            // 1563

    char* p = (char*)d_ws;
    unsigned* tmp  = (unsigned*)p;             p += (size_t)nbuckets * MAXSEG * 4;
    u16* csr2      = (u16*)p;                  p += (size_t)nbuckets * MAXSEG * 2;
    float* hf      = (float*)p;                p += (size_t)N * 64 * 4;      // h3 only
    u16* hwba      = (u16*)p;                  p += (size_t)(N + 1) * 64 * 2; // layer2 matmul out
    u16* hwbb      = (u16*)p;                  p += (size_t)(N + 1) * 64 * 2; // layer3 matmul out
    u16* xp        = (u16*)p;                  p += (size_t)(N + 1) * 16 * 2;
    int* row_start = (int*)p;                  p += (size_t)N * 4;
    int* row_cntp  = (int*)p;                  p += (size_t)N * 4;
    float* dinv    = (float*)p;                p += (size_t)N * 4;
    float* part    = (float*)p;                p += (size_t)gGB * 64 * 4;    // block partials
    int* gcnt      = (int*)p;                  p += 256 * 4;
    float* gsum    = (float*)p;                p += 64 * 4;

    hipMemsetAsync(gcnt, 0, 256 * 4, stream);   // gcnt only (gsum overwritten by reduce)

    const int* src = edge;
    const int* dst = edge + E;

    bin_kernel<<<nchunks, 1024, 0, stream>>>(src, dst, gcnt, tmp, hwba, hwbb, xp, E, N);
    csr_build<<<nbuckets, 1024, 0, stream>>>(tmp, gcnt, csr2, row_start, row_cntp, dinv, x, xp, N);

    l1l2<<<gMM, 256, 0, stream>>>(row_start, row_cntp, csr2, xp, dinv, W1, b1, W2, hwba, N);
    g2l3<<<gMM, 512, 0, stream>>>(row_start, row_cntp, csr2, hwba, dinv, b2, W3, hwbb, N);
    gather_b3<<<gGB, 256, 0, stream>>>(row_start, row_cntp, csr2, hwbb, dinv, b3, hf, part, N);
    gsum_reduce<<<64, 64, 0, stream>>>(part, gsum, gGB);

    final_kernel<<<S, 256, 0, stream>>>(hf, sheet_idx, sheet_feat, gsum,
                                        gW1, gb1, gW2, gb2, fW, fb,
                                        qW1, qb1, qW2, qb2, out, N, L);
}